// Round 7
// baseline (2625.425 us; speedup 1.0000x reference)
//
#include <hip/hip_runtime.h>

#define NG 8      // independent batch groups (16 rows each)

// One monotonic counter per group, 128 B apart. 8 arrivals/step (one per
// block; each certifies that block's h1[t] AND h2[t-1] stores). Zeroed by
// init_kernel (stream-ordered before the main kernel) every launch.
__device__ __attribute__((aligned(128))) unsigned int g_cnt[NG * 32];

typedef __attribute__((ext_vector_type(8))) short short8;
typedef __attribute__((ext_vector_type(4))) float floatx4;

// Split fp32 v into bf16 hi + bf16 lo (residual), packed (hi<<16)|lo.
__device__ __forceinline__ unsigned int split_pack(float v) {
    unsigned int u  = __float_as_uint(v);
    unsigned int hb = u & 0xffff0000u;          // truncated-bf16 hi, exact in fp32
    float r = v - __uint_as_float(hb);          // exact residual
    return hb | (__float_as_uint(r) >> 16);
}

__device__ __forceinline__ float sigmoidf_(float z) {
    return 1.0f / (1.0f + __expf(-z));
}

// ---- r4-proven device-coherent primitives (NO new asm this round) ----
// sc1 stores write through to the coherence point (L2 never dirtied => the
// release arrival's wbl2 is ~free). sc1 u64 loads used ONLY for the
// once-per-step block-cooperative staging. Relaxed RMW spin executes
// memory-side at L3 (never stale, no per-poll cache maintenance). No acquire
// fence anywhere => weights/x stay L1/L2-warm across all 512 steps.
__device__ __forceinline__ void st_coh(unsigned int* p, unsigned int v) {
    __hip_atomic_store(p, v, __ATOMIC_RELAXED, __HIP_MEMORY_SCOPE_AGENT);
}
__device__ __forceinline__ unsigned long long ld_coh64(const unsigned long long* p) {
    return __hip_atomic_load(p, __ATOMIC_RELAXED, __HIP_MEMORY_SCOPE_AGENT);
}
__device__ __forceinline__ unsigned int ld_rmw(unsigned int* p) {
    return __hip_atomic_fetch_add(p, 0u, __ATOMIC_RELAXED, __HIP_MEMORY_SCOPE_AGENT);
}
__device__ __forceinline__ void arrive(unsigned int* cnt) {
    __hip_atomic_fetch_add(cnt, 1u, __ATOMIC_RELEASE, __HIP_MEMORY_SCOPE_AGENT);
}
__device__ __forceinline__ void spin_ge(unsigned int* cnt, unsigned int target) {
    while (ld_rmw(cnt) < target) {}
}

// Block-cooperative staging of BOTH h tiles (h1: 16x256 uints, h2: 16x128)
// into XOR-swizzled LDS. 3072 u64 across 512 threads = 6 each; all loads
// issued before any LDS write. Swizzle: uint col c of row r stored at
// c ^ ((r&7)<<2) (flips bits 2-4 => 4-uint-aligned chunks move as units;
// identical mapping to the r4-proven stage_tile).
__device__ __forceinline__ void stage_both(unsigned int* ldsA, unsigned int* ldsB,
                                           const unsigned int* srcA, const unsigned int* srcB,
                                           int tid) {
    const unsigned long long* sA = (const unsigned long long*)srcA;
    const unsigned long long* sB = (const unsigned long long*)srcB;
    unsigned long long q[6];
#pragma unroll
    for (int j = 0; j < 4; ++j) q[j] = ld_coh64(sA + tid + 512 * j);
#pragma unroll
    for (int j = 4; j < 6; ++j) q[j] = ld_coh64(sB + tid + 512 * (j - 4));
#pragma unroll
    for (int j = 0; j < 4; ++j) {
        int f   = tid + 512 * j;
        int row = f >> 7;                        // 128 u64 per 256-uint row
        int c   = (f & 127) * 2;
        *(unsigned long long*)(ldsA + row * 256 + (c ^ ((row & 7) << 2))) = q[j];
    }
#pragma unroll
    for (int j = 4; j < 6; ++j) {
        int f   = tid + 512 * (j - 4);
        int row = f >> 6;                        // 64 u64 per 128-uint row
        int c   = (f & 63) * 2;
        *(unsigned long long*)(ldsB + row * 128 + (c ^ ((row & 7) << 2))) = q[j];
    }
}

// Unpack 8 packed hi/lo uints from swizzled LDS (i0 4-uint aligned; the
// second uint4 of the 8-chunk lives at i0 ^ 4).
__device__ __forceinline__ void unpack_lds(const unsigned int* lp, int i0, short8& ah, short8& al) {
    uint4 pa = *(const uint4*)(lp + i0);
    uint4 pb = *(const uint4*)(lp + (i0 ^ 4));
    unsigned int pv[8] = {pa.x, pa.y, pa.z, pa.w, pb.x, pb.y, pb.z, pb.w};
#pragma unroll
    for (int j = 0; j < 8; ++j) {
        ah[j] = (short)(pv[j] >> 16);
        al[j] = (short)(pv[j] & 0xffffu);
    }
}

__device__ __forceinline__ void cvt_x(const float* xp, short8& ah, short8& al) {
    float4 xa = *(const float4*)(xp);
    float4 xb = *(const float4*)(xp + 4);
    float xv[8] = {xa.x, xa.y, xa.z, xa.w, xb.x, xb.y, xb.z, xb.w};
#pragma unroll
    for (int j = 0; j < 8; ++j) {
        unsigned int u  = __float_as_uint(xv[j]);
        unsigned int hb = u & 0xffff0000u;
        float r = xv[j] - __uint_as_float(hb);
        ah[j] = (short)(u >> 16);
        al[j] = (short)(__float_as_uint(r) >> 16);
    }
}

// Merged-layer kernel. 8 blocks/group x 512 threads: waves 0-3 = layer1
// (8 units each, 2 coltiles, NKC=10), waves 4-7 = layer2 (4 units each,
// 1 coltile, NKC=12), layer2 lagging one step in-block.
//
// Block-step t (t=0..512):
//   L1 waves compute h1[t]   = f(h1[t-1], x[t])        (active t<512)
//   L2 waves compute h2[t-1] = f(h2[t-2], h1[t-1])     (active t>=1)
// Gate: cnt >= 8(t+1)  [init zeros-publish counts 8 => "step -1 done";
// each block's per-step arrival certifies its staging+compute+stores of the
// whole step]. 2-slot rings are safe under this gate: any writer of slot
// (t+1)&1 is gated on ALL blocks completing step t, which includes every
// straggler's staging read of the old tile in that slot.
//
// MFMA 16x16x32_bf16: A: m=lane&15,k=quad*8+j ; D: col=lane&15, row=quad*4+r
__global__ void __launch_bounds__(512, 2)
lstm_fused_kernel(const float* __restrict__ x,
                  const float* __restrict__ W1, const float* __restrict__ U1,
                  const float* __restrict__ b1,
                  const float* __restrict__ W2, const float* __restrict__ U2,
                  const float* __restrict__ b2,
                  float* __restrict__ out, unsigned int* __restrict__ ws)
{
    __shared__ float zex[8][16][17];         // per-wave gate-gather tiles
    __shared__ unsigned int ldsA[16 * 256];  // staged h1[t-1] (swizzled)
    __shared__ unsigned int ldsB[16 * 128];  // staged h2[t-2] (swizzled)
    unsigned int* h1pk = ws;                 // [2][128][256] packed hi/lo bf16
    unsigned int* h2pk = ws + 65536;         // [2][128][128]

    const int tid  = threadIdx.x;
    const int g    = blockIdx.x & 7;         // batch group
    const int blk  = blockIdx.x >> 3;        // 0..7
    const int wv   = tid >> 6;               // 0..7
    const bool l1w = (wv < 4);
    const int m0   = g * 16;
    unsigned int* cnt = &g_cnt[g * 32];

    const int lane = tid & 63;
    const int n    = lane & 15;
    const int quad = lane >> 4;
    const int gate = n >> 2;
    const int b_l  = lane >> 2;              // epilogue: batch-local 0..15
    const int ul   = lane & 3;               // epilogue: unit-local 0..3
    const int sw   = (n & 7) << 2;           // LDS read swizzle for this lane's row

    // role constants (wave-uniform)
    const int NKC = l1w ? 10 : 12;
    const int NC  = l1w ? 2 : 1;
    const int KX  = l1w ? 64 : 256;
    const int GW  = l1w ? 1024 : 512;
    const int UU  = l1w ? 256 : 128;
    const int u0  = l1w ? (blk * 4 + wv) * 8         // 32 L1 unit-waves x 8 = 256
                        : (blk * 4 + (wv - 4)) * 4;  // 32 L2 unit-waves x 4 = 128
    const float* Wm   = l1w ? W1 : W2;
    const float* Um   = l1w ? U1 : U2;
    const float* bias = l1w ? b1 : b2;

    // ---- one-time: weight B-fragments (hi/lo split), bias ----
    short8 bh[2][12], bl[2][12];
    float bias_v[2];
#pragma unroll
    for (int c = 0; c < 2; ++c) {
        if (c >= NC) { bias_v[c] = 0.f; continue; }
        const int col = gate * UU + u0 + c * 4 + (n & 3);
        bias_v[c] = bias[col];
#pragma unroll
        for (int kc = 0; kc < 12; ++kc) {
            if (kc >= NKC) continue;
#pragma unroll
            for (int j = 0; j < 8; ++j) {
                int k = kc * 32 + quad * 8 + j;
                float w = (k < KX) ? Wm[k * GW + col] : Um[(k - KX) * GW + col];
                unsigned int p = split_pack(w);
                bh[c][kc][j] = (short)(p >> 16);
                bl[c][kc][j] = (short)(p & 0xffffu);
            }
        }
    }

    // ---- zero the "step -1" h slice this wave owns (ws is poisoned) ----
#pragma unroll
    for (int c = 0; c < 2; ++c) {
        if (c >= NC) continue;
        if (l1w) st_coh(&h1pk[32768 + (m0 + b_l) * 256 + u0 + c * 4 + ul], 0u);
        else     st_coh(&h2pk[16384 + (m0 + b_l) * 128 + u0 + c * 4 + ul], 0u);
    }
    float cst[2] = {0.f, 0.f};

    __syncthreads();                          // drains each wave's zero stores
    if (tid == 0) arrive(cnt);                // => cnt reaches 8: "step -1 done"

    for (int t = 0; t <= 512; ++t) {
        // ---- x-part prologue (no recurrent dependency): off the
        // post-observe critical path ----
        floatx4 acc[2];
#pragma unroll
        for (int c = 0; c < 2; ++c)
            acc[c] = {bias_v[c], bias_v[c], bias_v[c], bias_v[c]};
        if (l1w && t < 512) {
            const float* xsrc = x + (size_t)(m0 + n) * (512 * 64) + t * 64;
#pragma unroll
            for (int kc = 0; kc < 2; ++kc) {
                short8 ah, al;
                cvt_x(xsrc + kc * 32 + quad * 8, ah, al);
#pragma unroll
                for (int c = 0; c < 2; ++c) {
                    acc[c] = __builtin_amdgcn_mfma_f32_16x16x32_bf16(ah, bh[c][kc], acc[c], 0, 0, 0);
                    acc[c] = __builtin_amdgcn_mfma_f32_16x16x32_bf16(ah, bl[c][kc], acc[c], 0, 0, 0);
                    acc[c] = __builtin_amdgcn_mfma_f32_16x16x32_bf16(al, bh[c][kc], acc[c], 0, 0, 0);
                }
            }
        }

        // ---- wait for step-(t-1) publishes (thread 0 spins; barrier
        // publishes the observation to the block) ----
        if (tid == 0) spin_ge(cnt, 8u * (unsigned)(t + 1));
        __syncthreads();

        // ---- block-cooperative staging: h1[t-1] and h2[t-2] ----
        stage_both(ldsA, ldsB,
                   h1pk + ((t + 1) & 1) * 32768 + m0 * 256,
                   h2pk + (t & 1) * 16384 + m0 * 128, tid);
        __syncthreads();

        const bool active = l1w ? (t < 512) : (t >= 1);
        if (active) {
            const int s = l1w ? t : (t - 1);

            // ---- recurrent MFMAs ----
#pragma unroll
            for (int kc = 0; kc < 12; ++kc) {
                if (kc >= NKC) continue;
                if (l1w && kc < 2) continue;             // x-part already done
                short8 ah, al;
                if (l1w)
                    unpack_lds(ldsA, n * 256 + (((kc - 2) * 32 + quad * 8) ^ sw), ah, al);
                else if (kc < 8)
                    unpack_lds(ldsA, n * 256 + ((kc * 32 + quad * 8) ^ sw), ah, al);
                else
                    unpack_lds(ldsB, n * 128 + (((kc - 8) * 32 + quad * 8) ^ sw), ah, al);
#pragma unroll
                for (int c = 0; c < 2; ++c) {
                    if (c >= NC) continue;
                    acc[c] = __builtin_amdgcn_mfma_f32_16x16x32_bf16(ah, bh[c][kc], acc[c], 0, 0, 0);
                    acc[c] = __builtin_amdgcn_mfma_f32_16x16x32_bf16(ah, bl[c][kc], acc[c], 0, 0, 0);
                    acc[c] = __builtin_amdgcn_mfma_f32_16x16x32_bf16(al, bh[c][kc], acc[c], 0, 0, 0);
                }
            }

            // ---- epilogue: per coltile, gate-gather via per-wave LDS tile.
            // Wave-level lgkmcnt(0) drains this wave's ds_writes before any
            // lane's read; memory clobber stops reordering. ----
#pragma unroll
            for (int c = 0; c < 2; ++c) {
                if (c >= NC) continue;
#pragma unroll
                for (int r = 0; r < 4; ++r) zex[wv][quad * 4 + r][n] = acc[c][r];
                asm volatile("s_waitcnt lgkmcnt(0)" ::: "memory");
                float zi = zex[wv][b_l][ 0 + ul];
                float zf = zex[wv][b_l][ 4 + ul];
                float zg = zex[wv][b_l][ 8 + ul];
                float zo = zex[wv][b_l][12 + ul];
                asm volatile("s_waitcnt lgkmcnt(0)" ::: "memory");
                float ig = sigmoidf_(zi);
                float fg = sigmoidf_(zf);
                float gg = fmaxf(zg, 0.f);
                float og = sigmoidf_(zo);
                cst[c] = fg * cst[c] + ig * gg;
                float h = og * fmaxf(cst[c], 0.f);
                unsigned int p = split_pack(h);
                int b = m0 + b_l;
                if (l1w) {
                    st_coh(&h1pk[(s & 1) * 32768 + b * 256 + u0 + c * 4 + ul], p);
                } else {
                    st_coh(&h2pk[(s & 1) * 16384 + b * 128 + u0 + c * 4 + ul], p);
                    if (s == 511) out[b * 128 + u0 + c * 4 + ul] = h;
                }
            }
        }

        // ---- publish: barrier drains all waves' sc1 stores (per-wave
        // vmcnt(0) before s_barrier), then one release arrival ----
        __syncthreads();
        if (tid == 0 && t < 512) arrive(cnt);
    }
}

// Pre-kernel (plain launch, cannot fail): zero barrier counters, write the
// diagnostic sentinel. Stream order publishes both to the main kernel.
// Failure signatures: absmax~7 => main never ran (launch issue);
// absmax~0.162 => main ran but produced zeros (coherence issue).
__global__ void init_kernel(float* __restrict__ out) {
    int t = blockIdx.x * 256 + threadIdx.x;
    if (t < NG * 32) g_cnt[t] = 0u;
    if (t < 16384) out[t] = 7.0f;
}

extern "C" void kernel_launch(void* const* d_in, const int* in_sizes, int n_in,
                              void* d_out, int out_size, void* d_ws, size_t ws_size,
                              hipStream_t stream) {
    const float* x  = (const float*)d_in[0];
    const float* W1 = (const float*)d_in[1];
    const float* U1 = (const float*)d_in[2];
    const float* b1 = (const float*)d_in[3];
    const float* W2 = (const float*)d_in[4];
    const float* U2 = (const float*)d_in[5];
    const float* b2 = (const float*)d_in[6];
    float* out = (float*)d_out;
    unsigned int* ws = (unsigned int*)d_ws;
    init_kernel<<<64, 256, 0, stream>>>(out);
    lstm_fused_kernel<<<64, 512, 0, stream>>>(x, W1, U1, b1, W2, U2, b2, out, ws);
}

// Round 8
// 2098.345 us; speedup vs baseline: 1.2512x; 1.2512x over previous
//
#include <hip/hip_runtime.h>

#define NG 8      // independent batch groups (16 rows each)

// Two monotonic counters per group, 128 B apart: [g*64]=cntA (layer1, 4
// arrivals/step), [g*64+32]=cntB (layer2, 2 arrivals/step). Zeroed by
// init_kernel (stream-ordered before the main kernel) every launch.
__device__ __attribute__((aligned(128))) unsigned int g_cnt[NG * 64];

typedef __attribute__((ext_vector_type(8))) short short8;
typedef __attribute__((ext_vector_type(4))) float floatx4;

// Split fp32 v into bf16 hi + bf16 lo (residual), packed (hi<<16)|lo.
__device__ __forceinline__ unsigned int split_pack(float v) {
    unsigned int u  = __float_as_uint(v);
    unsigned int hb = u & 0xffff0000u;          // truncated-bf16 hi, exact in fp32
    float r = v - __uint_as_float(hb);          // exact residual
    return hb | (__float_as_uint(r) >> 16);
}

__device__ __forceinline__ float sigmoidf_(float z) {
    return 1.0f / (1.0f + __expf(-z));
}

// ---- r4-proven device-coherent primitives ----
// sc1 stores write through to the coherence point (L2 never dirtied => the
// release arrival's wbl2 is ~free). sc1 u64 loads used ONLY for the
// once-per-step block-cooperative staging (r3 lesson: per-lane sc1 gathers
// regress 2x). Relaxed RMW spin executes memory-side at L3 (never stale, no
// per-poll cache maintenance -- r1/r2 lessons). No acquire fence anywhere =>
// weights/x stay L1/L2-warm across all 512 steps.
__device__ __forceinline__ void st_coh(unsigned int* p, unsigned int v) {
    __hip_atomic_store(p, v, __ATOMIC_RELAXED, __HIP_MEMORY_SCOPE_AGENT);
}
__device__ __forceinline__ unsigned long long ld_coh64(const unsigned long long* p) {
    return __hip_atomic_load(p, __ATOMIC_RELAXED, __HIP_MEMORY_SCOPE_AGENT);
}
__device__ __forceinline__ unsigned int ld_rmw(unsigned int* p) {
    return __hip_atomic_fetch_add(p, 0u, __ATOMIC_RELAXED, __HIP_MEMORY_SCOPE_AGENT);
}
__device__ __forceinline__ void arrive(unsigned int* cnt) {
    __hip_atomic_fetch_add(cnt, 1u, __ATOMIC_RELEASE, __HIP_MEMORY_SCOPE_AGENT);
}
// Dual spin: both RMWs issued back-to-back each iteration -> one L3 round
// trip covers both counters.
__device__ __forceinline__ void spin2(unsigned int* ca, unsigned int ta,
                                      unsigned int* cb, unsigned int tb) {
    for (;;) {
        unsigned int ra = ld_rmw(ca);
        unsigned int rb = ld_rmw(cb);
        if (ra >= ta && rb >= tb) return;
    }
}

// ---- LDS staging for 512-thread blocks (swizzle: uint col c of row r at
// c ^ ((r&7)<<2); XOR flips bits 2-4 only, so 4-uint-aligned chunks move as
// units -- identical mapping to the r4/r7-proven stagers) ----

// h1 tile: 16x256 uints = 2048 u64, 4 per thread. All loads before writes.
__device__ __forceinline__ void stage_h1(unsigned int* lds, const unsigned int* gsrc, int tid) {
    const unsigned long long* s64 = (const unsigned long long*)gsrc;
    unsigned long long q[4];
#pragma unroll
    for (int j = 0; j < 4; ++j) q[j] = ld_coh64(s64 + tid + 512 * j);
#pragma unroll
    for (int j = 0; j < 4; ++j) {
        int f   = tid + 512 * j;
        int row = f >> 7;                        // 128 u64 per 256-uint row
        int c   = (f & 127) * 2;
        *(unsigned long long*)(lds + row * 256 + (c ^ ((row & 7) << 2))) = q[j];
    }
}

// h1 (16x256) + h2 (16x128) tiles: 3072 u64, 6 per thread.
__device__ __forceinline__ void stage_h1h2(unsigned int* ldsA, unsigned int* ldsB,
                                           const unsigned int* srcA, const unsigned int* srcB,
                                           int tid) {
    const unsigned long long* sA = (const unsigned long long*)srcA;
    const unsigned long long* sB = (const unsigned long long*)srcB;
    unsigned long long q[6];
#pragma unroll
    for (int j = 0; j < 4; ++j) q[j] = ld_coh64(sA + tid + 512 * j);
#pragma unroll
    for (int j = 4; j < 6; ++j) q[j] = ld_coh64(sB + tid + 512 * (j - 4));
#pragma unroll
    for (int j = 0; j < 4; ++j) {
        int f   = tid + 512 * j;
        int row = f >> 7;
        int c   = (f & 127) * 2;
        *(unsigned long long*)(ldsA + row * 256 + (c ^ ((row & 7) << 2))) = q[j];
    }
#pragma unroll
    for (int j = 4; j < 6; ++j) {
        int f   = tid + 512 * (j - 4);
        int row = f >> 6;                        // 64 u64 per 128-uint row
        int c   = (f & 63) * 2;
        *(unsigned long long*)(ldsB + row * 128 + (c ^ ((row & 7) << 2))) = q[j];
    }
}

// Unpack 8 packed hi/lo uints from swizzled LDS (i0 4-uint aligned; the
// second uint4 of the 8-chunk lives at i0 ^ 4).
__device__ __forceinline__ void unpack_lds(const unsigned int* lp, int i0, short8& ah, short8& al) {
    uint4 pa = *(const uint4*)(lp + i0);
    uint4 pb = *(const uint4*)(lp + (i0 ^ 4));
    unsigned int pv[8] = {pa.x, pa.y, pa.z, pa.w, pb.x, pb.y, pb.z, pb.w};
#pragma unroll
    for (int j = 0; j < 8; ++j) {
        ah[j] = (short)(pv[j] >> 16);
        al[j] = (short)(pv[j] & 0xffffu);
    }
}

__device__ __forceinline__ void cvt_x(const float* xp, short8& ah, short8& al) {
    float4 xa = *(const float4*)(xp);
    float4 xb = *(const float4*)(xp + 4);
    float xv[8] = {xa.x, xa.y, xa.z, xa.w, xb.x, xb.y, xb.z, xb.w};
#pragma unroll
    for (int j = 0; j < 8; ++j) {
        unsigned int u  = __float_as_uint(xv[j]);
        unsigned int hb = u & 0xffff0000u;
        float r = xv[j] - __uint_as_float(hb);
        ah[j] = (short)(u >> 16);
        al[j] = (short)(__float_as_uint(r) >> 16);
    }
}

// One LSTM layer role for one batch group (16 rows). Wave owns 8 units x 4
// gates (2 coltiles). MFMA 16x16x32_bf16, hi/lo-split weights in registers.
// MFMA: A: m=lane&15,k=quad*8+j ; D: col=lane&15, row=quad*4+r
//
// Split-counter dependency schedule (r4-proven, scaled to 4+2 blocks; init
// arrivals = "step -1 done"):
//   L1@s : wait cntA>=4(s+1) [peers' h1[s-1]]  and (s>=2) cntB>=2s
//          [h1-slot free: L2 done s-2];  arrival at end => cntA=4(s+2)
//   L2@s : wait cntA>=4(s+2) [h1[s] ready]     and cntB>=2(s+1) [peers'
//          h2[s-1] + h2-slot free];      arrival at end => cntB=2(s+2)
// L1 runs up to 2 steps ahead of L2; neither waits on the other's per-step
// stragglers (r7 lesson: lockstep merging costs +34%).
template<int NKC, int KX, int GW, int UU, bool L1>
__device__ void lstm_role(const float* __restrict__ x,
                          const float* __restrict__ Wm, const float* __restrict__ Um,
                          const float* __restrict__ bias,
                          unsigned int* __restrict__ h1pk, unsigned int* __restrict__ h2pk,
                          float* __restrict__ out,
                          unsigned int* __restrict__ cntA, unsigned int* __restrict__ cntB,
                          int m0, int wid, float (*zex)[17],
                          unsigned int* __restrict__ ldsA, unsigned int* __restrict__ ldsB)
{
    const int tid  = threadIdx.x;
    const int lane = tid & 63;
    const int n    = lane & 15;
    const int quad = lane >> 4;
    const int gate = n >> 2;
    const int u0   = wid * 8;             // 8 units per wave (2 coltiles x 4)
    const int b_l  = lane >> 2;           // epilogue: batch-local 0..15
    const int ul   = lane & 3;            // epilogue: unit-local 0..3
    const int sw   = (n & 7) << 2;        // LDS read swizzle for this lane's row

    // ---- one-time: weight B-fragments (hi/lo split), bias ----
    short8 bh[2][NKC], bl[2][NKC];
    float bias_v[2];
#pragma unroll
    for (int c = 0; c < 2; ++c) {
        const int col = gate * UU + u0 + c * 4 + (n & 3);
        bias_v[c] = bias[col];
#pragma unroll
        for (int kc = 0; kc < NKC; ++kc) {
#pragma unroll
            for (int j = 0; j < 8; ++j) {
                int k = kc * 32 + quad * 8 + j;
                float w = (k < KX) ? Wm[k * GW + col] : Um[(k - KX) * GW + col];
                unsigned int p = split_pack(w);
                bh[c][kc][j] = (short)(p >> 16);
                bl[c][kc][j] = (short)(p & 0xffffu);
            }
        }
    }

    // ---- zero the "step -1" h slice this wave owns (ws is poisoned) ----
#pragma unroll
    for (int c = 0; c < 2; ++c) {
        if (L1) st_coh(&h1pk[32768 + (m0 + b_l) * 256 + u0 + c * 4 + ul], 0u);
        else    st_coh(&h2pk[16384 + (m0 + b_l) * 128 + u0 + c * 4 + ul], 0u);
    }
    float cst[2] = {0.f, 0.f};

    __syncthreads();                      // drains each wave's zero stores
    if (tid == 0) arrive(L1 ? cntA : cntB);

    for (int s = 0; s < 512; ++s) {
        // ---- wait for inputs (thread 0 spins, barrier publishes to block) ----
        if (tid == 0) {
            if (L1) spin2(cntA, 4u * (s + 1), cntB, (s >= 2) ? 2u * (unsigned)s : 0u);
            else    spin2(cntA, 4u * (s + 2), cntB, 2u * (s + 1));
        }
        __syncthreads();

        // ---- block-cooperative staging of h tiles into swizzled LDS ----
        if (L1) {
            stage_h1(ldsA, h1pk + ((s + 1) & 1) * 32768 + m0 * 256, tid);        // h1[s-1]
        } else {
            stage_h1h2(ldsA, ldsB,
                       h1pk + (s & 1) * 32768 + m0 * 256,                        // h1[s]
                       h2pk + ((s + 1) & 1) * 16384 + m0 * 128, tid);            // h2[s-1]
        }
        __syncthreads();

        // ---- compute step s ----
        floatx4 acc[2];
#pragma unroll
        for (int c = 0; c < 2; ++c)
            acc[c] = {bias_v[c], bias_v[c], bias_v[c], bias_v[c]};

        const float* xsrc = L1 ? (x + (size_t)(m0 + n) * (512 * 64) + s * 64) : nullptr;

#pragma unroll
        for (int kc = 0; kc < NKC; ++kc) {
            short8 ah, al;
            if (L1) {
                if (kc < 2) cvt_x(xsrc + kc * 32 + quad * 8, ah, al);
                else        unpack_lds(ldsA, n * 256 + (((kc - 2) * 32 + quad * 8) ^ sw), ah, al);
            } else {
                if (kc < 8) unpack_lds(ldsA, n * 256 + ((kc * 32 + quad * 8) ^ sw), ah, al);
                else        unpack_lds(ldsB, n * 128 + (((kc - 8) * 32 + quad * 8) ^ sw), ah, al);
            }
#pragma unroll
            for (int c = 0; c < 2; ++c) {
                acc[c] = __builtin_amdgcn_mfma_f32_16x16x32_bf16(ah, bh[c][kc], acc[c], 0, 0, 0);
                acc[c] = __builtin_amdgcn_mfma_f32_16x16x32_bf16(ah, bl[c][kc], acc[c], 0, 0, 0);
                acc[c] = __builtin_amdgcn_mfma_f32_16x16x32_bf16(al, bh[c][kc], acc[c], 0, 0, 0);
            }
        }

        // ---- epilogue: per coltile, gate-gather via per-wave LDS tile.
        // Wave-level lgkmcnt(0) drains the ds_writes of ALL lanes of this
        // wave before any lane's read; memory clobber stops reordering. ----
#pragma unroll
        for (int c = 0; c < 2; ++c) {
#pragma unroll
            for (int r = 0; r < 4; ++r) zex[quad * 4 + r][n] = acc[c][r];
            asm volatile("s_waitcnt lgkmcnt(0)" ::: "memory");
            float zi = zex[b_l][ 0 + ul];
            float zf = zex[b_l][ 4 + ul];
            float zg = zex[b_l][ 8 + ul];
            float zo = zex[b_l][12 + ul];
            asm volatile("s_waitcnt lgkmcnt(0)" ::: "memory");
            float ig = sigmoidf_(zi);
            float fg = sigmoidf_(zf);
            float gg = fmaxf(zg, 0.f);
            float og = sigmoidf_(zo);
            cst[c] = fg * cst[c] + ig * gg;
            float h = og * fmaxf(cst[c], 0.f);
            unsigned int p = split_pack(h);
            int b = m0 + b_l;
            if (L1) {
                st_coh(&h1pk[(s & 1) * 32768 + b * 256 + u0 + c * 4 + ul], p);
            } else {
                st_coh(&h2pk[(s & 1) * 16384 + b * 128 + u0 + c * 4 + ul], p);
                if (s == 511) out[b * 128 + u0 + c * 4 + ul] = h;
            }
        }

        // ---- publish: barrier drains all waves' sc1 stores (per-wave
        // vmcnt(0) before s_barrier), then one release arrival ----
        __syncthreads();
        if (tid == 0) arrive(L1 ? cntA : cntB);
    }
}

__global__ void __launch_bounds__(512, 1)
lstm_fused_kernel(const float* __restrict__ x,
                  const float* __restrict__ W1, const float* __restrict__ U1,
                  const float* __restrict__ b1,
                  const float* __restrict__ W2, const float* __restrict__ U2,
                  const float* __restrict__ b2,
                  float* __restrict__ out, unsigned int* __restrict__ ws)
{
    __shared__ float zex[8][16][17];         // per-wave gate-gather tiles
    __shared__ unsigned int ldsA[16 * 256];  // staged h1 tile (swizzled)
    __shared__ unsigned int ldsB[16 * 128];  // staged h2 tile (swizzled, L2-role)
    unsigned int* h1pk = ws;                 // [2][128][256] packed hi/lo bf16
    unsigned int* h2pk = ws + 65536;         // [2][128][128]
    const int g    = blockIdx.x & 7;         // batch group
    const int role = blockIdx.x >> 3;        // 0..3 layer1, 4..5 layer2
    const int wv   = threadIdx.x >> 6;       // wave 0..7
    const int m0   = g * 16;
    unsigned int* cntA = &g_cnt[g * 64];
    unsigned int* cntB = &g_cnt[g * 64 + 32];
    if (role < 4) {
        // layer1: 4 blocks x 8 waves = 32 unit-waves x 8 units = 256 units
        lstm_role<10, 64, 1024, 256, true >(x, W1, U1, b1, h1pk, h2pk, out,
                                            cntA, cntB, m0, role * 8 + wv, zex[wv], ldsA, ldsB);
    } else {
        // layer2: 2 blocks x 8 waves = 16 unit-waves x 8 units = 128 units
        lstm_role<12, 256, 512, 128, false>(x, W2, U2, b2, h1pk, h2pk, out,
                                            cntA, cntB, m0, (role - 4) * 8 + wv, zex[wv], ldsA, ldsB);
    }
}

// Pre-kernel (plain launch, cannot fail): zero barrier counters, write the
// diagnostic sentinel. Stream order publishes both to the main kernel.
// Failure signatures: absmax~7 => main never ran (launch issue);
// absmax~0.162 => main ran but produced zeros (coherence issue).
__global__ void init_kernel(float* __restrict__ out) {
    int t = blockIdx.x * 256 + threadIdx.x;
    if (t < NG * 64) g_cnt[t] = 0u;
    if (t < 16384) out[t] = 7.0f;
}

extern "C" void kernel_launch(void* const* d_in, const int* in_sizes, int n_in,
                              void* d_out, int out_size, void* d_ws, size_t ws_size,
                              hipStream_t stream) {
    const float* x  = (const float*)d_in[0];
    const float* W1 = (const float*)d_in[1];
    const float* U1 = (const float*)d_in[2];
    const float* b1 = (const float*)d_in[3];
    const float* W2 = (const float*)d_in[4];
    const float* U2 = (const float*)d_in[5];
    const float* b2 = (const float*)d_in[6];
    float* out = (float*)d_out;
    unsigned int* ws = (unsigned int*)d_ws;
    init_kernel<<<64, 256, 0, stream>>>(out);
    lstm_fused_kernel<<<48, 512, 0, stream>>>(x, W1, U1, b1, W2, U2, b2, out, ws);
}